// Round 1
// baseline (156.099 us; speedup 1.0000x reference)
//
#include <hip/hip_runtime.h>
#include <math.h>

#define K_DIM 64
#define DEG 32

// Sum across all 64 lanes of the wave; every lane gets the result.
__device__ __forceinline__ float wave_sum(float v) {
    #pragma unroll
    for (int off = 32; off > 0; off >>= 1)
        v += __shfl_xor(v, off, 64);
    return v;
}

// nn.Embedding(max_norm=1) lookup normalization: e * min(1, 1/max(||e||,1e-12))
__device__ __forceinline__ float renorm_scale(float n2) {
    float n = sqrtf(n2);
    return fminf(1.0f, 1.0f / fmaxf(n, 1e-12f));
}

// Hop 0: one wave per frontier row i in [0, N0).
// agg0[i,k] = (sum_d e)^2 - sum_d e^2 + tgt0[i,k],  e = renorm(entity_emb[nbr0[i,d]])
__global__ __launch_bounds__(256) void gafm_hop0(
    const float* __restrict__ entity_emb,
    const int*   __restrict__ node_ids0,
    const int*   __restrict__ nbr0,
    float*       __restrict__ agg0,
    int n0)
{
    int wave = (int)((blockIdx.x * blockDim.x + threadIdx.x) >> 6);
    int lane = threadIdx.x & 63;
    if (wave >= n0) return;

    const int* nb = nbr0 + (size_t)wave * DEG;
    float S = 0.0f, Q = 0.0f;
    #pragma unroll 4
    for (int d = 0; d < DEG; ++d) {
        int idx = nb[d];                       // wave-uniform -> scalar load
        float e = entity_emb[(size_t)idx * K_DIM + lane];  // coalesced 256B
        float scale = renorm_scale(wave_sum(e * e));
        e *= scale;
        S += e;
        Q += e * e;
    }
    int tidx = node_ids0[wave];
    float t = entity_emb[(size_t)tidx * K_DIM + lane];
    t *= renorm_scale(wave_sum(t * t));

    agg0[(size_t)wave * K_DIM + lane] = S * S - Q + t;
}

// Hop 1 + score: one wave per batch row b in [0, B).
// ent1 = agg0[nbr1_idx[b,d]] (plain gather, NO renorm);
// items = fm(ent1) + renorm(entity_emb[item_ids[b]]);
// logit = sigmoid(dot(renorm(user_emb[u[b]]), items))
__global__ __launch_bounds__(256) void gafm_hop1(
    const float* __restrict__ entity_emb,
    const float* __restrict__ user_emb,
    const int*   __restrict__ u_ids,
    const int*   __restrict__ item_ids,
    const int*   __restrict__ nbr1_idx,
    const float* __restrict__ agg0,
    float*       __restrict__ out,
    int nb_rows)
{
    int wave = (int)((blockIdx.x * blockDim.x + threadIdx.x) >> 6);
    int lane = threadIdx.x & 63;
    if (wave >= nb_rows) return;

    const int* nb = nbr1_idx + (size_t)wave * DEG;
    float S = 0.0f, Q = 0.0f;
    #pragma unroll 4
    for (int d = 0; d < DEG; ++d) {
        int j = nb[d];
        float e = agg0[(size_t)j * K_DIM + lane];
        S += e;
        Q += e * e;
    }
    float agg1 = S * S - Q;

    int ti = item_ids[wave];
    float t = entity_emb[(size_t)ti * K_DIM + lane];
    t *= renorm_scale(wave_sum(t * t));
    float items = agg1 + t;

    int ui = u_ids[wave];
    float uu = user_emb[(size_t)ui * K_DIM + lane];
    uu *= renorm_scale(wave_sum(uu * uu));

    float dot = wave_sum(uu * items);
    if (lane == 0)
        out[wave] = 1.0f / (1.0f + expf(-dot));
}

extern "C" void kernel_launch(void* const* d_in, const int* in_sizes, int n_in,
                              void* d_out, int out_size, void* d_ws, size_t ws_size,
                              hipStream_t stream) {
    // Input order (setup_inputs dict order):
    // 0 entity_emb [1e6,64] f32   1 user_emb [1e5,64] f32
    // 2 Wa [64,64] f32 (DEAD: softmax over singleton axis == 1)
    // 3 ba [64]    f32 (DEAD)     4 Wh [64,1] f32 (DEAD)   5 bh [1] f32 (DEAD)
    // 6 u [B] i32                 7 item_ids [B] i32
    // 8 nbr1_idx [B,32] i32       9 node_ids0 [N0] i32     10 nbr0 [N0,32] i32
    const float* entity_emb = (const float*)d_in[0];
    const float* user_emb   = (const float*)d_in[1];
    const int*   u_ids      = (const int*)d_in[6];
    const int*   item_ids   = (const int*)d_in[7];
    const int*   nbr1_idx   = (const int*)d_in[8];
    const int*   node_ids0  = (const int*)d_in[9];
    const int*   nbr0       = (const int*)d_in[10];
    float*       out        = (float*)d_out;

    const int B  = in_sizes[6];   // 2048
    const int N0 = in_sizes[9];   // 65536

    float* agg0 = (float*)d_ws;   // N0 * 64 * 4 = 16 MB scratch

    // 4 waves per 256-thread block, one wave per row.
    int blocks0 = (N0 + 3) / 4;
    gafm_hop0<<<blocks0, 256, 0, stream>>>(entity_emb, node_ids0, nbr0, agg0, N0);

    int blocks1 = (B + 3) / 4;
    gafm_hop1<<<blocks1, 256, 0, stream>>>(entity_emb, user_emb, u_ids, item_ids,
                                           nbr1_idx, agg0, out, B);
}

// Round 2
// 96.939 us; speedup vs baseline: 1.6103x; 1.6103x over previous
//
#include <hip/hip_runtime.h>
#include <math.h>

#define K_DIM 64
#define DEG 32

// Sum across all 64 lanes of the wave; every lane gets the result.
__device__ __forceinline__ float wave_sum(float v) {
    #pragma unroll
    for (int off = 32; off > 0; off >>= 1)
        v += __shfl_xor(v, off, 64);
    return v;
}

// nn.Embedding(max_norm=1): scale = min(1, 1/max(||e||,1e-12)).
// Renorm only shrinks rows with norm > 1; for norm <= 1 (incl. 0) scale is 1.
// rsq(n2) > 1 exactly when norm < 1, so fminf(1, rsq(n2)) matches (rsq(0)=inf -> 1).
__device__ __forceinline__ float renorm_scale(float n2) {
    return fminf(1.0f, __frsqrt_rn(n2));
}

// Hop 0: 4 rows per wave; 16 lanes per row, each lane owns a float4 (4 of k=64).
// agg0[i,:] = (sum_d e)^2 - sum_d e^2 + renorm(entity_emb[node_ids0[i]])
__global__ __launch_bounds__(256) void gafm_hop0(
    const float4* __restrict__ emb4,      // entity_emb viewed as [N_ENT][16] float4
    const int*    __restrict__ node_ids0,
    const int*    __restrict__ nbr0,
    float4*       __restrict__ agg0_4,    // [N0][16] float4
    int n0)
{
    const int lane = threadIdx.x & 63;
    const int wave_in_blk = threadIdx.x >> 6;
    const int c   = lane & 15;            // chunk: covers k = 4c..4c+3
    const int row = blockIdx.x * 16 + wave_in_blk * 4 + (lane >> 4);
    if (row >= n0) return;

    const int* nb = nbr0 + (size_t)row * DEG;

    float Sx = 0.f, Sy = 0.f, Sz = 0.f, Sw = 0.f;
    float Qx = 0.f, Qy = 0.f, Qz = 0.f, Qw = 0.f;

    #pragma unroll 4
    for (int d = 0; d < DEG; ++d) {
        int idx = nb[d];                          // same addr across 16-lane group
        float4 v = emb4[(size_t)idx * 16 + c];    // 16 lanes x 16B = full 256B row
        float n2 = fmaf(v.x, v.x, fmaf(v.y, v.y, fmaf(v.z, v.z, v.w * v.w)));
        // reduce over the 16 lanes of this row-group (offsets stay in-group)
        n2 += __shfl_xor(n2, 1, 64);
        n2 += __shfl_xor(n2, 2, 64);
        n2 += __shfl_xor(n2, 4, 64);
        n2 += __shfl_xor(n2, 8, 64);
        float r = renorm_scale(n2);
        float ex = v.x * r, ey = v.y * r, ez = v.z * r, ew = v.w * r;
        Sx += ex; Sy += ey; Sz += ez; Sw += ew;
        Qx = fmaf(ex, ex, Qx); Qy = fmaf(ey, ey, Qy);
        Qz = fmaf(ez, ez, Qz); Qw = fmaf(ew, ew, Qw);
    }

    int tidx = node_ids0[row];
    float4 t = emb4[(size_t)tidx * 16 + c];
    float tn2 = fmaf(t.x, t.x, fmaf(t.y, t.y, fmaf(t.z, t.z, t.w * t.w)));
    tn2 += __shfl_xor(tn2, 1, 64);
    tn2 += __shfl_xor(tn2, 2, 64);
    tn2 += __shfl_xor(tn2, 4, 64);
    tn2 += __shfl_xor(tn2, 8, 64);
    float tr = renorm_scale(tn2);

    float4 o;
    o.x = fmaf(Sx, Sx, -Qx) + t.x * tr;
    o.y = fmaf(Sy, Sy, -Qy) + t.y * tr;
    o.z = fmaf(Sz, Sz, -Qz) + t.z * tr;
    o.w = fmaf(Sw, Sw, -Qw) + t.w * tr;
    agg0_4[(size_t)row * 16 + c] = o;
}

// Hop 1 + score: one wave per batch row (lane = k). Only 2048 rows -> negligible.
__global__ __launch_bounds__(256) void gafm_hop1(
    const float* __restrict__ entity_emb,
    const float* __restrict__ user_emb,
    const int*   __restrict__ u_ids,
    const int*   __restrict__ item_ids,
    const int*   __restrict__ nbr1_idx,
    const float* __restrict__ agg0,
    float*       __restrict__ out,
    int nb_rows)
{
    int wave = (int)((blockIdx.x * blockDim.x + threadIdx.x) >> 6);
    int lane = threadIdx.x & 63;
    if (wave >= nb_rows) return;

    const int* nb = nbr1_idx + (size_t)wave * DEG;
    float S = 0.0f, Q = 0.0f;
    #pragma unroll 4
    for (int d = 0; d < DEG; ++d) {
        int j = nb[d];
        float e = agg0[(size_t)j * K_DIM + lane];  // plain gather, NO renorm
        S += e;
        Q = fmaf(e, e, Q);
    }
    float agg1 = fmaf(S, S, -Q);

    int ti = item_ids[wave];
    float t = entity_emb[(size_t)ti * K_DIM + lane];
    t *= renorm_scale(wave_sum(t * t));
    float items = agg1 + t;

    int ui = u_ids[wave];
    float uu = user_emb[(size_t)ui * K_DIM + lane];
    uu *= renorm_scale(wave_sum(uu * uu));

    float dot = wave_sum(uu * items);
    if (lane == 0)
        out[wave] = 1.0f / (1.0f + expf(-dot));
}

extern "C" void kernel_launch(void* const* d_in, const int* in_sizes, int n_in,
                              void* d_out, int out_size, void* d_ws, size_t ws_size,
                              hipStream_t stream) {
    // 0 entity_emb [1e6,64] f32   1 user_emb [1e5,64] f32
    // 2..5 Wa/ba/Wh/bh (DEAD: softmax over singleton axis == ones)
    // 6 u [B] i32   7 item_ids [B] i32   8 nbr1_idx [B,32] i32
    // 9 node_ids0 [N0] i32   10 nbr0 [N0,32] i32
    const float* entity_emb = (const float*)d_in[0];
    const float* user_emb   = (const float*)d_in[1];
    const int*   u_ids      = (const int*)d_in[6];
    const int*   item_ids   = (const int*)d_in[7];
    const int*   nbr1_idx   = (const int*)d_in[8];
    const int*   node_ids0  = (const int*)d_in[9];
    const int*   nbr0       = (const int*)d_in[10];
    float*       out        = (float*)d_out;

    const int B  = in_sizes[6];   // 2048
    const int N0 = in_sizes[9];   // 65536

    float* agg0 = (float*)d_ws;   // N0 * 64 * 4 = 16 MB scratch

    // hop0: 16 rows per 256-thread block (4 waves x 4 rows)
    int blocks0 = (N0 + 15) / 16;
    gafm_hop0<<<blocks0, 256, 0, stream>>>((const float4*)entity_emb, node_ids0,
                                           nbr0, (float4*)agg0, N0);

    // hop1: one wave per row
    int blocks1 = (B + 3) / 4;
    gafm_hop1<<<blocks1, 256, 0, stream>>>(entity_emb, user_emb, u_ids, item_ids,
                                           nbr1_idx, agg0, out, B);
}

// Round 3
// 91.570 us; speedup vs baseline: 1.7047x; 1.0586x over previous
//
#include <hip/hip_runtime.h>
#include <math.h>

#define K_DIM 64
#define DEG 32

// Sum across all 64 lanes of the wave; every lane gets the result.
__device__ __forceinline__ float wave_sum(float v) {
    #pragma unroll
    for (int off = 32; off > 0; off >>= 1)
        v += __shfl_xor(v, off, 64);
    return v;
}

// nn.Embedding(max_norm=1): scale = min(1, 1/max(||e||,1e-12)).
// rsq(n2) > 1 iff norm < 1, rsq(0)=inf -> min gives 1. Matches reference.
__device__ __forceinline__ float renorm_scale(float n2) {
    return fminf(1.0f, __frsqrt_rn(n2));
}

// Hop 0: 4 rows per wave; 16 lanes per row-group, each lane owns a float4.
// Indices preloaded (1 int2/lane = the group's 32 indices), broadcast via
// in-group shfl; gathers issued in batches of 8 for memory-level parallelism.
__global__ __launch_bounds__(256) void gafm_hop0(
    const float4* __restrict__ emb4,      // entity_emb as [N_ENT][16] float4
    const int*    __restrict__ node_ids0,
    const int*    __restrict__ nbr0,
    float4*       __restrict__ agg0_4,    // [N0][16] float4
    int n0)
{
    const int lane = threadIdx.x & 63;
    const int wave_in_blk = threadIdx.x >> 6;
    const int c   = lane & 15;            // chunk: covers k = 4c..4c+3
    const int g16 = lane & 48;            // base lane of this 16-lane row-group
    const int row = blockIdx.x * 16 + wave_in_blk * 4 + (lane >> 4);
    if (row >= n0) return;                // whole 16-lane group exits together

    // Preload this row's 32 neighbor indices: lane j of the group holds
    // elements 2j and 2j+1. One coalesced 8B load per lane.
    const int2 my_idx = ((const int2*)(nbr0 + (size_t)row * DEG))[c];

    float Sx = 0.f, Sy = 0.f, Sz = 0.f, Sw = 0.f;
    float Qx = 0.f, Qy = 0.f, Qz = 0.f, Qw = 0.f;

    #pragma unroll
    for (int b = 0; b < DEG / 8; ++b) {
        float4 buf[8];
        // Issue 8 independent gathers (indices come from registers via shfl,
        // no memory dependency in the chain).
        #pragma unroll
        for (int t = 0; t < 8; ++t) {
            const int d = b * 8 + t;
            const int src = g16 | (d >> 1);                 // stays in-group
            const int idx = __shfl((d & 1) ? my_idx.y : my_idx.x, src, 64);
            buf[t] = emb4[(size_t)idx * 16 + c];
        }
        // Consume.
        #pragma unroll
        for (int t = 0; t < 8; ++t) {
            float4 v = buf[t];
            float n2 = fmaf(v.x, v.x, fmaf(v.y, v.y, fmaf(v.z, v.z, v.w * v.w)));
            n2 += __shfl_xor(n2, 1, 64);
            n2 += __shfl_xor(n2, 2, 64);
            n2 += __shfl_xor(n2, 4, 64);
            n2 += __shfl_xor(n2, 8, 64);
            float r = renorm_scale(n2);
            float ex = v.x * r, ey = v.y * r, ez = v.z * r, ew = v.w * r;
            Sx += ex; Sy += ey; Sz += ez; Sw += ew;
            Qx = fmaf(ex, ex, Qx); Qy = fmaf(ey, ey, Qy);
            Qz = fmaf(ez, ez, Qz); Qw = fmaf(ew, ew, Qw);
        }
    }

    int tidx = node_ids0[row];
    float4 t = emb4[(size_t)tidx * 16 + c];
    float tn2 = fmaf(t.x, t.x, fmaf(t.y, t.y, fmaf(t.z, t.z, t.w * t.w)));
    tn2 += __shfl_xor(tn2, 1, 64);
    tn2 += __shfl_xor(tn2, 2, 64);
    tn2 += __shfl_xor(tn2, 4, 64);
    tn2 += __shfl_xor(tn2, 8, 64);
    float tr = renorm_scale(tn2);

    float4 o;
    o.x = fmaf(Sx, Sx, -Qx) + t.x * tr;
    o.y = fmaf(Sy, Sy, -Qy) + t.y * tr;
    o.z = fmaf(Sz, Sz, -Qz) + t.z * tr;
    o.w = fmaf(Sw, Sw, -Qw) + t.w * tr;
    agg0_4[(size_t)row * 16 + c] = o;
}

// Hop 1 + score: one wave per batch row (lane = k). 2048 rows -> negligible.
__global__ __launch_bounds__(256) void gafm_hop1(
    const float* __restrict__ entity_emb,
    const float* __restrict__ user_emb,
    const int*   __restrict__ u_ids,
    const int*   __restrict__ item_ids,
    const int*   __restrict__ nbr1_idx,
    const float* __restrict__ agg0,
    float*       __restrict__ out,
    int nb_rows)
{
    int wave = (int)((blockIdx.x * blockDim.x + threadIdx.x) >> 6);
    int lane = threadIdx.x & 63;
    if (wave >= nb_rows) return;

    const int* nb = nbr1_idx + (size_t)wave * DEG;
    float S = 0.0f, Q = 0.0f;
    #pragma unroll 8
    for (int d = 0; d < DEG; ++d) {
        int j = nb[d];
        float e = agg0[(size_t)j * K_DIM + lane];  // plain gather, NO renorm
        S += e;
        Q = fmaf(e, e, Q);
    }
    float agg1 = fmaf(S, S, -Q);

    int ti = item_ids[wave];
    float t = entity_emb[(size_t)ti * K_DIM + lane];
    t *= renorm_scale(wave_sum(t * t));
    float items = agg1 + t;

    int ui = u_ids[wave];
    float uu = user_emb[(size_t)ui * K_DIM + lane];
    uu *= renorm_scale(wave_sum(uu * uu));

    float dot = wave_sum(uu * items);
    if (lane == 0)
        out[wave] = 1.0f / (1.0f + expf(-dot));
}

extern "C" void kernel_launch(void* const* d_in, const int* in_sizes, int n_in,
                              void* d_out, int out_size, void* d_ws, size_t ws_size,
                              hipStream_t stream) {
    // 0 entity_emb [1e6,64] f32   1 user_emb [1e5,64] f32
    // 2..5 Wa/ba/Wh/bh (DEAD: softmax over singleton axis == ones)
    // 6 u [B] i32   7 item_ids [B] i32   8 nbr1_idx [B,32] i32
    // 9 node_ids0 [N0] i32   10 nbr0 [N0,32] i32
    const float* entity_emb = (const float*)d_in[0];
    const float* user_emb   = (const float*)d_in[1];
    const int*   u_ids      = (const int*)d_in[6];
    const int*   item_ids   = (const int*)d_in[7];
    const int*   nbr1_idx   = (const int*)d_in[8];
    const int*   node_ids0  = (const int*)d_in[9];
    const int*   nbr0       = (const int*)d_in[10];
    float*       out        = (float*)d_out;

    const int B  = in_sizes[6];   // 2048
    const int N0 = in_sizes[9];   // 65536

    float* agg0 = (float*)d_ws;   // N0 * 64 * 4 = 16 MB scratch

    // hop0: 16 rows per 256-thread block (4 waves x 4 rows)
    int blocks0 = (N0 + 15) / 16;
    gafm_hop0<<<blocks0, 256, 0, stream>>>((const float4*)entity_emb, node_ids0,
                                           nbr0, (float4*)agg0, N0);

    // hop1: one wave per row
    int blocks1 = (B + 3) / 4;
    gafm_hop1<<<blocks1, 256, 0, stream>>>(entity_emb, user_emb, u_ids, item_ids,
                                           nbr1_idx, agg0, out, B);
}